// Round 8
// baseline (890.057 us; speedup 1.0000x reference)
//
#include <hip/hip_runtime.h>

// ---------------------------------------------------------------------------
// Round 8: ABLATION ROUND. conv_full (= round-7 kernel) still produces the
// real output; three repeated phase-isolation kernels run first so their
// per-dispatch durations appear in the rocprof top-5.
//   abl_stage: R x (halo-zero + x^2 staging + barrier)
//   abl_kloop: stage once, R x (pure LDS+MFMA K-loop)      [laundered addrs]
//   abl_merge: prologue once, R x (merge tree + tr + store + partials)
// ---------------------------------------------------------------------------

#define A_MORR 0.8578f
#define R_MORR 0.8578f
#define TR_C1 (A_MORR * A_MORR + R_MORR * R_MORR)
#define TR_C2 (-2.0f * A_MORR * R_MORR)
#define TR_C3 (1.0f + (A_MORR * R_MORR) * (A_MORR * R_MORR))
#define BN_EPS 1e-5f

#define NPIX 65536
#define X2_LO 26112          // 6*34*128: lo plane offset
#define SMEM_BYTES 52224
#define NBLK 512

#define STAGE_R 64
#define KLOOP_R 48
#define MERGE_R 24

typedef __attribute__((ext_vector_type(8))) short bf16x8;
typedef __attribute__((ext_vector_type(16))) float f32x16;

__device__ __forceinline__ int launder(int v) {
    int o;
    asm volatile("v_mov_b32 %0, %1" : "=v"(o) : "v"(v));
    return o;
}

__device__ __forceinline__ void bf16split(float s, unsigned short& h, unsigned short& l) {
    union { float f; unsigned u; } cv; cv.f = s;
    unsigned r = (cv.u + 0x7fffu + ((cv.u >> 16) & 1u)) & 0xffff0000u;
    h = (unsigned short)(r >> 16);
    union { unsigned u; float f; } hv; hv.u = r;
    float lo = s - hv.f;
    cv.f = lo;
    unsigned r2 = cv.u + 0x7fffu + ((cv.u >> 16) & 1u);
    l = (unsigned short)(r2 >> 16);
}

// ---------------------------------------------------------------------------
__global__ __launch_bounds__(256) void prep_kernel(const float* __restrict__ w,
                                                   char* __restrict__ wfrag) {
    int gtid = blockIdx.x * 256 + threadIdx.x;
    if (gtid < 36864) {
        int j    = gtid & 7;
        int lane = (gtid >> 3) & 63;
        int okm  = gtid >> 9;
        int mt   = okm & 1;
        int ks   = (okm >> 1) & 3;
        int off  = okm >> 3;
        int oc   = mt * 32 + (lane & 31);
        int c    = ks * 16 + (lane >> 5) * 8 + j;
        int kg   = c * 9 + off;
        float val = w[(oc >> 3) * 576 + (kg >> 3) * 8 + ((oc - kg) & 7)];
        unsigned short h, l;
        bf16split(val, h, l);
        ((unsigned short*)(wfrag + okm * 2048))[lane * 8 + j] = h;
        ((unsigned short*)(wfrag + okm * 2048 + 1024))[lane * 8 + j] = l;
    }
}

// ---------------------------------------------------------------------------
// Shared phase helpers (byte-identical math to round 7)
// ---------------------------------------------------------------------------
__device__ __forceinline__ void halo_zero(char* smem, int tid) {
    if (tid < 192) {
        int prec = tid & 1;
        int g    = (tid >> 1) & 7;
        int rc   = tid >> 4;
        int r    = rc >> 1;
        int c    = (rc & 1) ? 33 : 0;
        *(uint4*)(smem + prec * X2_LO + ((r * 34 + c) << 7) + (g << 4)) = uint4{0, 0, 0, 0};
    }
}

__device__ __forceinline__ void stage_x2(char* smem, const float* __restrict__ x,
                                         int rt, int b, int tid, int opq) {
    const int rh  = tid & 1;
    const int co  = (tid >> 1) & 7;
    const int chp = tid >> 4;
    const float* xb = x + (size_t)(b * 64 + 2 * chp) * 1024 + opq;
#pragma unroll
    for (int r3 = 0; r3 < 3; ++r3) {
        int rr = rh * 3 + r3;
        int gr = rt * 4 - 1 + rr;
        float4 a0 = {0.f, 0.f, 0.f, 0.f}, a1 = {0.f, 0.f, 0.f, 0.f};
        if (gr >= 0 && gr < 32) {
            const float* rp = xb + gr * 32 + co * 4;
            a0 = *(const float4*)rp;
            a1 = *(const float4*)(rp + 1024);
        }
        float s0[4] = {a0.x * a0.x, a0.y * a0.y, a0.z * a0.z, a0.w * a0.w};
        float s1[4] = {a1.x * a1.x, a1.y * a1.y, a1.z * a1.z, a1.w * a1.w};
#pragma unroll
        for (int i = 0; i < 4; ++i) {
            unsigned short h0, l0, h1, l1;
            bf16split(s0[i], h0, l0);
            bf16split(s1[i], h1, l1);
            int c    = 1 + co * 4 + i;
            int base = ((rr * 34 + c) << 7) + (((chp >> 2) ^ (c & 7)) << 4)
                     + ((chp & 3) << 2);
            *(unsigned*)(smem + base)         = (unsigned)h0 | ((unsigned)h1 << 16);
            *(unsigned*)(smem + X2_LO + base) = (unsigned)l0 | ((unsigned)l1 << 16);
        }
    }
}

__device__ __forceinline__ void preload_w(const char* __restrict__ wfrag,
                                          int wmt, int kq, int lane,
                                          bf16x8* wh, bf16x8* wl) {
    const char* wbase = wfrag + (size_t)wmt * 2048 + kq * 4096 + lane * 16;
#pragma unroll
    for (int t = 0; t < 9; ++t) {
        wh[t] = *(const bf16x8*)(wbase + t * 16384);
        wl[t] = *(const bf16x8*)(wbase + t * 16384 + 1024);
    }
}

__device__ __forceinline__ void kloop(const char* smem, const bf16x8* wh, const bf16x8* wl,
                                      int kq, int hs, int col, int opq,
                                      f32x16& acc0, f32x16& acc1, f32x16& acc2, f32x16& acc3) {
#pragma unroll
    for (int dj = 0; dj < 3; ++dj) {
        const int c = col + dj;
        const int g = (((kq * 2 + hs) ^ (c & 7)) << 4);
        bf16x8 bh[6], bl[6];
#pragma unroll
        for (int rr = 0; rr < 6; ++rr) {
            const char* sp = smem + ((rr * 34 + c) << 7) + g + opq;
            bh[rr] = *(const bf16x8*)sp;
            bl[rr] = *(const bf16x8*)(sp + X2_LO);
        }
#pragma unroll
        for (int di = 0; di < 3; ++di) {
            const bf16x8 ah = wh[di * 3 + dj];
            const bf16x8 al = wl[di * 3 + dj];
            acc0 = __builtin_amdgcn_mfma_f32_32x32x16_bf16(ah, bh[di + 0], acc0, 0, 0, 0);
            acc1 = __builtin_amdgcn_mfma_f32_32x32x16_bf16(ah, bh[di + 1], acc1, 0, 0, 0);
            acc2 = __builtin_amdgcn_mfma_f32_32x32x16_bf16(ah, bh[di + 2], acc2, 0, 0, 0);
            acc3 = __builtin_amdgcn_mfma_f32_32x32x16_bf16(ah, bh[di + 3], acc3, 0, 0, 0);
            acc0 = __builtin_amdgcn_mfma_f32_32x32x16_bf16(ah, bl[di + 0], acc0, 0, 0, 0);
            acc1 = __builtin_amdgcn_mfma_f32_32x32x16_bf16(ah, bl[di + 1], acc1, 0, 0, 0);
            acc2 = __builtin_amdgcn_mfma_f32_32x32x16_bf16(ah, bl[di + 2], acc2, 0, 0, 0);
            acc3 = __builtin_amdgcn_mfma_f32_32x32x16_bf16(ah, bl[di + 3], acc3, 0, 0, 0);
            acc0 = __builtin_amdgcn_mfma_f32_32x32x16_bf16(al, bh[di + 0], acc0, 0, 0, 0);
            acc1 = __builtin_amdgcn_mfma_f32_32x32x16_bf16(al, bh[di + 1], acc1, 0, 0, 0);
            acc2 = __builtin_amdgcn_mfma_f32_32x32x16_bf16(al, bh[di + 2], acc2, 0, 0, 0);
            acc3 = __builtin_amdgcn_mfma_f32_32x32x16_bf16(al, bh[di + 3], acc3, 0, 0, 0);
        }
    }
}

__device__ __forceinline__ void merge_epi(char* smem, float* __restrict__ out,
                                          float* __restrict__ partials,
                                          int bid, int b, int rt, int tid,
                                          int lane, int wmt, int kq, int col, int hs,
                                          f32x16& acc0, f32x16& acc1, f32x16& acc2, f32x16& acc3) {
    float* mg = (float*)smem;
#define SLOT_W() do {                                                          \
    _Pragma("unroll") for (int j = 0; j < 16; ++j) {                           \
        mg[((wmt * 4 + 0) * 16 + j) * 64 + lane] = acc0[j];                    \
        mg[((wmt * 4 + 1) * 16 + j) * 64 + lane] = acc1[j];                    \
        mg[((wmt * 4 + 2) * 16 + j) * 64 + lane] = acc2[j];                    \
        mg[((wmt * 4 + 3) * 16 + j) * 64 + lane] = acc3[j];                    \
    } } while (0)
#define SLOT_A() do {                                                          \
    _Pragma("unroll") for (int j = 0; j < 16; ++j) {                           \
        acc0[j] += mg[((wmt * 4 + 0) * 16 + j) * 64 + lane];                   \
        acc1[j] += mg[((wmt * 4 + 1) * 16 + j) * 64 + lane];                   \
        acc2[j] += mg[((wmt * 4 + 2) * 16 + j) * 64 + lane];                   \
        acc3[j] += mg[((wmt * 4 + 3) * 16 + j) * 64 + lane];                   \
    } } while (0)

    __syncthreads();                     // S1
    if (kq == 3) SLOT_W();
    __syncthreads();                     // S2
    if (kq == 1) SLOT_A();
    __syncthreads();                     // S3
    if (kq == 2) SLOT_W();
    __syncthreads();                     // S4
    if (kq == 0) SLOT_A();
    __syncthreads();                     // S5
    if (kq == 1) SLOT_W();
    __syncthreads();                     // S6

    float* red1 = (float*)(smem + 32768);
    float* red2 = red1 + 64 * 33;

    if (kq == 0) {
        SLOT_A();
        float ts1[16], ts2[16];
#pragma unroll
        for (int j = 0; j < 16; ++j) { ts1[j] = 0.f; ts2[j] = 0.f; }
        const size_t obase = ((size_t)b * 64 + wmt * 32) * 1024 + rt * 128;
#define ROW_EPI(R, ACC) do {                                                   \
    _Pragma("unroll") for (int j = 0; j < 16; ++j) {                           \
        float cp = __cosf(ACC[j]);                                             \
        float t  = fmaf(TR_C2, cp, TR_C1) / fmaf(TR_C2, cp, TR_C3);            \
        int ocl  = (j & 3) + 8 * (j >> 2) + 4 * hs;                            \
        out[obase + (size_t)ocl * 1024 + (R) * 32 + col] = t;                  \
        ts1[j] += t; ts2[j] += t * t;                                          \
    } } while (0)
        ROW_EPI(0, acc0);
        ROW_EPI(1, acc1);
        ROW_EPI(2, acc2);
        ROW_EPI(3, acc3);
#pragma unroll
        for (int j = 0; j < 16; ++j) {
            int ocl = (j & 3) + 8 * (j >> 2) + 4 * hs;
            red1[(wmt * 32 + ocl) * 33 + col] = ts1[j];
            red2[(wmt * 32 + ocl) * 33 + col] = ts2[j];
        }
#undef ROW_EPI
    }
    __syncthreads();                     // S7
    if (tid < 64) {
        float s1 = 0.f, s2 = 0.f;
#pragma unroll
        for (int q = 0; q < 32; ++q) {
            s1 += red1[tid * 33 + q];
            s2 += red2[tid * 33 + q];
        }
        partials[(size_t)tid * NBLK + bid]        = s1;
        partials[(size_t)(64 + tid) * NBLK + bid] = s2;
    }
#undef SLOT_W
#undef SLOT_A
}

// ---------------------------------------------------------------------------
// Ablation kernels
// ---------------------------------------------------------------------------
__global__ __launch_bounds__(512, 2) void abl_stage(const float* __restrict__ x) {
    const int rt = blockIdx.x, b = blockIdx.y, tid = threadIdx.x;
    __shared__ __align__(16) char smem[SMEM_BYTES];
    halo_zero(smem, tid);
    for (int r = 0; r < STAGE_R; ++r) {
        int opq = launder(r) >> 17;      // runtime 0, compile-time opaque
        stage_x2(smem, x, rt, b, tid, opq);
        __syncthreads();
    }
    unsigned kv = *(unsigned*)(smem + ((tid & 1023) << 5));
    asm volatile("" :: "v"(kv));
}

__global__ __launch_bounds__(512, 2) void abl_kloop(const float* __restrict__ x,
                                                    const char* __restrict__ wfrag) {
    const int rt = blockIdx.x, b = blockIdx.y, tid = threadIdx.x;
    const int lane = tid & 63, wv = tid >> 6;
    const int wmt = wv & 1, kq = wv >> 1;
    const int col = lane & 31, hs = lane >> 5;
    __shared__ __align__(16) char smem[SMEM_BYTES];
    bf16x8 wh[9], wl[9];
    preload_w(wfrag, wmt, kq, lane, wh, wl);
    halo_zero(smem, tid);
    stage_x2(smem, x, rt, b, tid, 0);
    __syncthreads();
    f32x16 acc0, acc1, acc2, acc3;
#pragma unroll
    for (int i = 0; i < 16; ++i) { acc0[i] = 0.f; acc1[i] = 0.f; acc2[i] = 0.f; acc3[i] = 0.f; }
    for (int r = 0; r < KLOOP_R; ++r) {
        int opq = launder(r) >> 17;
        kloop(smem, wh, wl, kq, hs, col, opq, acc0, acc1, acc2, acc3);
    }
    float kv = acc0[0] + acc1[5] + acc2[10] + acc3[15];
    asm volatile("" :: "v"(kv));
}

__global__ __launch_bounds__(512, 2) void abl_merge(const float* __restrict__ x,
                                                    const char* __restrict__ wfrag,
                                                    float* __restrict__ out,
                                                    float* __restrict__ partials) {
    const int rt = blockIdx.x, b = blockIdx.y, tid = threadIdx.x;
    const int bid = b * 8 + rt;
    const int lane = tid & 63, wv = tid >> 6;
    const int wmt = wv & 1, kq = wv >> 1;
    const int col = lane & 31, hs = lane >> 5;
    __shared__ __align__(16) char smem[SMEM_BYTES];
    bf16x8 wh[9], wl[9];
    preload_w(wfrag, wmt, kq, lane, wh, wl);
    halo_zero(smem, tid);
    stage_x2(smem, x, rt, b, tid, 0);
    __syncthreads();
    f32x16 acc0, acc1, acc2, acc3;
#pragma unroll
    for (int i = 0; i < 16; ++i) { acc0[i] = 0.f; acc1[i] = 0.f; acc2[i] = 0.f; acc3[i] = 0.f; }
    kloop(smem, wh, wl, kq, hs, col, 0, acc0, acc1, acc2, acc3);
    for (int r = 0; r < MERGE_R; ++r) {
        merge_epi(smem, out, partials, bid, b, rt, tid, lane, wmt, kq, col, hs,
                  acc0, acc1, acc2, acc3);
    }
}

// ---------------------------------------------------------------------------
// The real conv kernel (round-7 structure, unchanged semantics)
// ---------------------------------------------------------------------------
__global__ __launch_bounds__(512, 2) void conv_full(const float* __restrict__ x,
                                                    const char* __restrict__ wfrag,
                                                    float* __restrict__ out,
                                                    float* __restrict__ partials) {
    const int rt = blockIdx.x, b = blockIdx.y, tid = threadIdx.x;
    const int bid = b * 8 + rt;
    const int lane = tid & 63, wv = tid >> 6;
    const int wmt = wv & 1, kq = wv >> 1;
    const int col = lane & 31, hs = lane >> 5;
    __shared__ __align__(16) char smem[SMEM_BYTES];
    bf16x8 wh[9], wl[9];
    preload_w(wfrag, wmt, kq, lane, wh, wl);
    halo_zero(smem, tid);
    stage_x2(smem, x, rt, b, tid, 0);
    __syncthreads();
    f32x16 acc0, acc1, acc2, acc3;
#pragma unroll
    for (int i = 0; i < 16; ++i) { acc0[i] = 0.f; acc1[i] = 0.f; acc2[i] = 0.f; acc3[i] = 0.f; }
    kloop(smem, wh, wl, kq, hs, col, 0, acc0, acc1, acc2, acc3);
    merge_epi(smem, out, partials, bid, b, rt, tid, lane, wmt, kq, col, hs,
              acc0, acc1, acc2, acc3);
}

// ---------------------------------------------------------------------------
__global__ __launch_bounds__(512) void stats_kernel(const float* __restrict__ partials,
                                                    const float* __restrict__ gamma,
                                                    const float* __restrict__ beta,
                                                    float* __restrict__ ss) {
    const int c   = blockIdx.x;
    const int tid = threadIdx.x;
    __shared__ float r1[512], r2[512];
    r1[tid] = partials[(size_t)c * NBLK + tid];
    r2[tid] = partials[(size_t)(64 + c) * NBLK + tid];
    __syncthreads();
#pragma unroll
    for (int s = 256; s > 0; s >>= 1) {
        if (tid < s) {
            r1[tid] += r1[tid + s];
            r2[tid] += r2[tid + s];
        }
        __syncthreads();
    }
    if (tid == 0) {
        const float invN = 1.0f / (float)NPIX;
        float mean = r1[0] * invN;
        float var  = r2[0] * invN - mean * mean;
        float sc   = gamma[c] * rsqrtf(var + BN_EPS);
        ss[c]      = sc;
        ss[64 + c] = beta[c] - mean * sc;
    }
}

__global__ __launch_bounds__(256) void norm_kernel(float* __restrict__ out,
                                                   const float* __restrict__ ss) {
    int i = blockIdx.x * 256 + threadIdx.x;
    float4 v = ((float4*)out)[i];
    int oc = (i >> 8) & 63;
    float sc = ss[oc];
    float sh = ss[64 + oc];
    v.x = fminf(1.0f, fmaxf(-1.0f, fmaf(v.x, sc, sh)));
    v.y = fminf(1.0f, fmaxf(-1.0f, fmaf(v.y, sc, sh)));
    v.z = fminf(1.0f, fmaxf(-1.0f, fmaf(v.z, sc, sh)));
    v.w = fminf(1.0f, fmaxf(-1.0f, fmaf(v.w, sc, sh)));
    ((float4*)out)[i] = v;
}

// ---------------------------------------------------------------------------
extern "C" void kernel_launch(void* const* d_in, const int* in_sizes, int n_in,
                              void* d_out, int out_size, void* d_ws, size_t ws_size,
                              hipStream_t stream) {
    const float* x     = (const float*)d_in[0];
    const float* w     = (const float*)d_in[1];
    const float* gamma = (const float*)d_in[2];
    const float* beta  = (const float*)d_in[3];
    float* out = (float*)d_out;

    char*  wfrag    = (char*)d_ws;                          // 147456 B
    float* partials = (float*)((char*)d_ws + 147456);       // 128*512 floats
    float* ss       = partials + 128 * NBLK;                // 128 floats

    hipLaunchKernelGGL(prep_kernel, dim3(144), dim3(256), 0, stream, w, wfrag);

    // --- ablation probes (outputs discarded / overwritten) ---
    hipLaunchKernelGGL(abl_stage, dim3(8, 64), dim3(512), 0, stream, x);
    hipLaunchKernelGGL(abl_kloop, dim3(8, 64), dim3(512), 0, stream, x, wfrag);
    hipLaunchKernelGGL(abl_merge, dim3(8, 64), dim3(512), 0, stream, x, wfrag, out, partials);

    // --- real pipeline ---
    hipLaunchKernelGGL(conv_full, dim3(8, 64), dim3(512), 0, stream, x, wfrag, out, partials);
    hipLaunchKernelGGL(stats_kernel, dim3(64), dim3(512), 0, stream, partials, gamma, beta, ss);
    hipLaunchKernelGGL(norm_kernel, dim3(4096), dim3(256), 0, stream, out, ss);
}

// Round 9
// 44.451 us; speedup vs baseline: 20.0231x; 20.0231x over previous
//
#include <hip/hip_runtime.h>

// ---------------------------------------------------------------------------
// ConvBlock: y = clip(BN(tr(conv3x3(x^2, Wconv))), -1, 1)
// Wconv[oc][c][di][dj] = weight[oc>>3][(c*9+3di+dj)>>3][(oc-(c*9+3di+dj))&7]
// GEMM: A = Wconv (M=64 oc), B = im2col(x^2) (N=65536 px), K=576.
// bf16 MFMA 32x32x16, 3-pass hi/lo split.
// Round 9: persistent 2-tile blocks (1/CU), double-buffered LDS staging,
// t1 global loads issued before t0's MFMA burst (latency hidden under MFMA).
// Merge scratch reuses the consumed buffer -> 104 KB dynamic LDS total.
// ---------------------------------------------------------------------------

#define A_MORR 0.8578f
#define R_MORR 0.8578f
#define TR_C1 (A_MORR * A_MORR + R_MORR * R_MORR)
#define TR_C2 (-2.0f * A_MORR * R_MORR)
#define TR_C3 (1.0f + (A_MORR * R_MORR) * (A_MORR * R_MORR))
#define BN_EPS 1e-5f

#define NPIX 65536
#define X2_LO 26112          // lo plane offset within one buffer
#define BUF_BYTES 52224      // one x2 buffer (hi+lo)
#define SMEM_TOTAL 104448    // two buffers
#define NBLK 512             // partial slots (one per row-tile x batch)

typedef __attribute__((ext_vector_type(8))) short bf16x8;
typedef __attribute__((ext_vector_type(16))) float f32x16;

__device__ __forceinline__ void bf16split(float s, unsigned short& h, unsigned short& l) {
    union { float f; unsigned u; } cv; cv.f = s;
    unsigned r = (cv.u + 0x7fffu + ((cv.u >> 16) & 1u)) & 0xffff0000u;
    h = (unsigned short)(r >> 16);
    union { unsigned u; float f; } hv; hv.u = r;
    float lo = s - hv.f;
    cv.f = lo;
    unsigned r2 = cv.u + 0x7fffu + ((cv.u >> 16) & 1u);
    l = (unsigned short)(r2 >> 16);
}

// ---------------------------------------------------------------------------
// Kernel A: fragment-ready bf16 hi/lo weights.
// wfrag[off*8 + ks*2 + mt][prec][lane][8ch] : 72 * 2048 B
// ---------------------------------------------------------------------------
__global__ __launch_bounds__(256) void prep_kernel(const float* __restrict__ w,
                                                   char* __restrict__ wfrag) {
    int gtid = blockIdx.x * 256 + threadIdx.x;
    if (gtid < 36864) {
        int j    = gtid & 7;
        int lane = (gtid >> 3) & 63;
        int okm  = gtid >> 9;
        int mt   = okm & 1;
        int ks   = (okm >> 1) & 3;
        int off  = okm >> 3;
        int oc   = mt * 32 + (lane & 31);
        int c    = ks * 16 + (lane >> 5) * 8 + j;
        int kg   = c * 9 + off;
        float val = w[(oc >> 3) * 576 + (kg >> 3) * 8 + ((oc - kg) & 7)];
        unsigned short h, l;
        bf16split(val, h, l);
        ((unsigned short*)(wfrag + okm * 2048))[lane * 8 + j] = h;
        ((unsigned short*)(wfrag + okm * 2048 + 1024))[lane * 8 + j] = l;
    }
}

// ---------------------------------------------------------------------------
// Phase helpers (math identical to rounds 6-8)
// ---------------------------------------------------------------------------
__device__ __forceinline__ void halo_zero(char* buf, int tid) {
    if (tid < 192) {
        int prec = tid & 1;
        int g    = (tid >> 1) & 7;
        int rc   = tid >> 4;             // 0..11
        int r    = rc >> 1;
        int c    = (rc & 1) ? 33 : 0;
        *(uint4*)(buf + prec * X2_LO + ((r * 34 + c) << 7) + (g << 4)) = uint4{0, 0, 0, 0};
    }
}

__device__ __forceinline__ void stage_load(float4 (&pre)[3][2], const float* __restrict__ x,
                                           int rt, int b, int tid) {
    const int rh  = tid & 1;
    const int co  = (tid >> 1) & 7;
    const int chp = tid >> 4;
    const float* xb = x + (size_t)(b * 64 + 2 * chp) * 1024;
#pragma unroll
    for (int r3 = 0; r3 < 3; ++r3) {
        int rr = rh * 3 + r3;
        int gr = rt * 4 - 1 + rr;
        float4 a0 = {0.f, 0.f, 0.f, 0.f}, a1 = {0.f, 0.f, 0.f, 0.f};
        if (gr >= 0 && gr < 32) {
            const float* rp = xb + gr * 32 + co * 4;
            a0 = *(const float4*)rp;
            a1 = *(const float4*)(rp + 1024);
        }
        pre[r3][0] = a0;
        pre[r3][1] = a1;
    }
}

__device__ __forceinline__ void stage_write(char* buf, const float4 (&pre)[3][2], int tid) {
    const int rh  = tid & 1;
    const int co  = (tid >> 1) & 7;
    const int chp = tid >> 4;
#pragma unroll
    for (int r3 = 0; r3 < 3; ++r3) {
        int rr = rh * 3 + r3;
        const float4 a0 = pre[r3][0];
        const float4 a1 = pre[r3][1];
        float s0[4] = {a0.x * a0.x, a0.y * a0.y, a0.z * a0.z, a0.w * a0.w};
        float s1[4] = {a1.x * a1.x, a1.y * a1.y, a1.z * a1.z, a1.w * a1.w};
#pragma unroll
        for (int i = 0; i < 4; ++i) {
            unsigned short h0, l0, h1, l1;
            bf16split(s0[i], h0, l0);
            bf16split(s1[i], h1, l1);
            int c    = 1 + co * 4 + i;
            int base = ((rr * 34 + c) << 7) + (((chp >> 2) ^ (c & 7)) << 4)
                     + ((chp & 3) << 2);
            *(unsigned*)(buf + base)         = (unsigned)h0 | ((unsigned)h1 << 16);
            *(unsigned*)(buf + X2_LO + base) = (unsigned)l0 | ((unsigned)l1 << 16);
        }
    }
}

__device__ __forceinline__ void preload_w(const char* __restrict__ wfrag,
                                          int wmt, int kq, int lane,
                                          bf16x8* wh, bf16x8* wl) {
    const char* wbase = wfrag + (size_t)wmt * 2048 + kq * 4096 + lane * 16;
#pragma unroll
    for (int t = 0; t < 9; ++t) {
        wh[t] = *(const bf16x8*)(wbase + t * 16384);
        wl[t] = *(const bf16x8*)(wbase + t * 16384 + 1024);
    }
}

__device__ __forceinline__ void kloop(const char* buf, const bf16x8* wh, const bf16x8* wl,
                                      int kq, int hs, int col,
                                      f32x16& acc0, f32x16& acc1, f32x16& acc2, f32x16& acc3) {
#pragma unroll
    for (int dj = 0; dj < 3; ++dj) {
        const int c = col + dj;
        const int g = (((kq * 2 + hs) ^ (c & 7)) << 4);
        bf16x8 bh[6], bl[6];
#pragma unroll
        for (int rr = 0; rr < 6; ++rr) {
            const char* sp = buf + ((rr * 34 + c) << 7) + g;
            bh[rr] = *(const bf16x8*)sp;
            bl[rr] = *(const bf16x8*)(sp + X2_LO);
        }
#pragma unroll
        for (int di = 0; di < 3; ++di) {
            const bf16x8 ah = wh[di * 3 + dj];
            const bf16x8 al = wl[di * 3 + dj];
            acc0 = __builtin_amdgcn_mfma_f32_32x32x16_bf16(ah, bh[di + 0], acc0, 0, 0, 0);
            acc1 = __builtin_amdgcn_mfma_f32_32x32x16_bf16(ah, bh[di + 1], acc1, 0, 0, 0);
            acc2 = __builtin_amdgcn_mfma_f32_32x32x16_bf16(ah, bh[di + 2], acc2, 0, 0, 0);
            acc3 = __builtin_amdgcn_mfma_f32_32x32x16_bf16(ah, bh[di + 3], acc3, 0, 0, 0);
            acc0 = __builtin_amdgcn_mfma_f32_32x32x16_bf16(ah, bl[di + 0], acc0, 0, 0, 0);
            acc1 = __builtin_amdgcn_mfma_f32_32x32x16_bf16(ah, bl[di + 1], acc1, 0, 0, 0);
            acc2 = __builtin_amdgcn_mfma_f32_32x32x16_bf16(ah, bl[di + 2], acc2, 0, 0, 0);
            acc3 = __builtin_amdgcn_mfma_f32_32x32x16_bf16(ah, bl[di + 3], acc3, 0, 0, 0);
            acc0 = __builtin_amdgcn_mfma_f32_32x32x16_bf16(al, bh[di + 0], acc0, 0, 0, 0);
            acc1 = __builtin_amdgcn_mfma_f32_32x32x16_bf16(al, bh[di + 1], acc1, 0, 0, 0);
            acc2 = __builtin_amdgcn_mfma_f32_32x32x16_bf16(al, bh[di + 2], acc2, 0, 0, 0);
            acc3 = __builtin_amdgcn_mfma_f32_32x32x16_bf16(al, bh[di + 3], acc3, 0, 0, 0);
        }
    }
}

__device__ __forceinline__ void merge_epi(char* scratch, float* __restrict__ out,
                                          float* __restrict__ partials,
                                          int bid, int b, int rt, int tid,
                                          int lane, int wmt, int kq, int col, int hs,
                                          f32x16& acc0, f32x16& acc1, f32x16& acc2, f32x16& acc3) {
    float* mg = (float*)scratch;
#define SLOT_W() do {                                                          \
    _Pragma("unroll") for (int j = 0; j < 16; ++j) {                           \
        mg[((wmt * 4 + 0) * 16 + j) * 64 + lane] = acc0[j];                    \
        mg[((wmt * 4 + 1) * 16 + j) * 64 + lane] = acc1[j];                    \
        mg[((wmt * 4 + 2) * 16 + j) * 64 + lane] = acc2[j];                    \
        mg[((wmt * 4 + 3) * 16 + j) * 64 + lane] = acc3[j];                    \
    } } while (0)
#define SLOT_A() do {                                                          \
    _Pragma("unroll") for (int j = 0; j < 16; ++j) {                           \
        acc0[j] += mg[((wmt * 4 + 0) * 16 + j) * 64 + lane];                   \
        acc1[j] += mg[((wmt * 4 + 1) * 16 + j) * 64 + lane];                   \
        acc2[j] += mg[((wmt * 4 + 2) * 16 + j) * 64 + lane];                   \
        acc3[j] += mg[((wmt * 4 + 3) * 16 + j) * 64 + lane];                   \
    } } while (0)

    __syncthreads();                     // S1
    if (kq == 3) SLOT_W();
    __syncthreads();                     // S2
    if (kq == 1) SLOT_A();
    __syncthreads();                     // S3
    if (kq == 2) SLOT_W();
    __syncthreads();                     // S4
    if (kq == 0) SLOT_A();
    __syncthreads();                     // S5
    if (kq == 1) SLOT_W();
    __syncthreads();                     // S6

    float* red1 = (float*)(scratch + 32768);       // [64][33]
    float* red2 = red1 + 64 * 33;                  // [64][33]

    if (kq == 0) {
        SLOT_A();
        float ts1[16], ts2[16];
#pragma unroll
        for (int j = 0; j < 16; ++j) { ts1[j] = 0.f; ts2[j] = 0.f; }
        const size_t obase = ((size_t)b * 64 + wmt * 32) * 1024 + rt * 128;
#define ROW_EPI(R, ACC) do {                                                   \
    _Pragma("unroll") for (int j = 0; j < 16; ++j) {                           \
        float cp = __cosf(ACC[j]);                                             \
        float t  = fmaf(TR_C2, cp, TR_C1) / fmaf(TR_C2, cp, TR_C3);            \
        int ocl  = (j & 3) + 8 * (j >> 2) + 4 * hs;                            \
        out[obase + (size_t)ocl * 1024 + (R) * 32 + col] = t;                  \
        ts1[j] += t; ts2[j] += t * t;                                          \
    } } while (0)
        ROW_EPI(0, acc0);
        ROW_EPI(1, acc1);
        ROW_EPI(2, acc2);
        ROW_EPI(3, acc3);
#pragma unroll
        for (int j = 0; j < 16; ++j) {
            int ocl = (j & 3) + 8 * (j >> 2) + 4 * hs;
            red1[(wmt * 32 + ocl) * 33 + col] = ts1[j];
            red2[(wmt * 32 + ocl) * 33 + col] = ts2[j];
        }
#undef ROW_EPI
    }
    __syncthreads();                     // S7
    if (tid < 64) {
        float s1 = 0.f, s2 = 0.f;
#pragma unroll
        for (int q = 0; q < 32; ++q) {
            s1 += red1[tid * 33 + q];
            s2 += red2[tid * 33 + q];
        }
        partials[(size_t)tid * NBLK + bid]        = s1;
        partials[(size_t)(64 + tid) * NBLK + bid] = s2;
    }
#undef SLOT_W
#undef SLOT_A
}

// ---------------------------------------------------------------------------
// Kernel B: persistent 2-tile conv. grid (4,64) = 256 blocks = 1/CU.
// Tiles rt0=2*bx, rt1=2*bx+1. Double-buffered LDS; t1 loads issued pre-MFMA.
// ---------------------------------------------------------------------------
__global__ __launch_bounds__(512, 2) void conv_kernel(const float* __restrict__ x,
                                                      const char* __restrict__ wfrag,
                                                      float* __restrict__ out,
                                                      float* __restrict__ partials) {
    extern __shared__ __align__(16) char smem[];
    char* buf0 = smem;
    char* buf1 = smem + BUF_BYTES;

    const int bx  = blockIdx.x;          // 0..3
    const int b   = blockIdx.y;
    const int rt0 = 2 * bx;
    const int rt1 = 2 * bx + 1;
    const int tid = threadIdx.x;

    const int lane = tid & 63;
    const int wv   = tid >> 6;
    const int wmt  = wv & 1;
    const int kq   = wv >> 1;
    const int col  = lane & 31;
    const int hs   = lane >> 5;

    bf16x8 wh[9], wl[9];
    preload_w(wfrag, wmt, kq, lane, wh, wl);

    halo_zero(buf0, tid);
    halo_zero(buf1, tid);

    // stage tile 0
    {
        float4 p0[3][2];
        stage_load(p0, x, rt0, b, tid);
        stage_write(buf0, p0, tid);
    }
    __syncthreads();

    f32x16 acc0, acc1, acc2, acc3;
#pragma unroll
    for (int i = 0; i < 16; ++i) { acc0[i] = 0.f; acc1[i] = 0.f; acc2[i] = 0.f; acc3[i] = 0.f; }

    // ---- tile 0 compute with tile 1 prefetch ----
    float4 p1[3][2];
    stage_load(p1, x, rt1, b, tid);      // global loads in flight during MFMA
    kloop(buf0, wh, wl, kq, hs, col, acc0, acc1, acc2, acc3);
    stage_write(buf1, p1, tid);          // waits loads, square/split, LDS write
    __syncthreads();                     // buf1 ready; buf0 reads done

    merge_epi(buf0, out, partials, b * 8 + rt0, b, rt0, tid,
              lane, wmt, kq, col, hs, acc0, acc1, acc2, acc3);

    // ---- tile 1 compute ----
#pragma unroll
    for (int i = 0; i < 16; ++i) { acc0[i] = 0.f; acc1[i] = 0.f; acc2[i] = 0.f; acc3[i] = 0.f; }
    kloop(buf1, wh, wl, kq, hs, col, acc0, acc1, acc2, acc3);

    merge_epi(buf0, out, partials, b * 8 + rt1, b, rt1, tid,
              lane, wmt, kq, col, hs, acc0, acc1, acc2, acc3);
}

// ---------------------------------------------------------------------------
// Kernel C: reduce per-tile partials -> BN scale/shift. grid 64, block 512.
// ---------------------------------------------------------------------------
__global__ __launch_bounds__(512) void stats_kernel(const float* __restrict__ partials,
                                                    const float* __restrict__ gamma,
                                                    const float* __restrict__ beta,
                                                    float* __restrict__ ss) {
    const int c   = blockIdx.x;
    const int tid = threadIdx.x;
    __shared__ float r1[512], r2[512];
    r1[tid] = partials[(size_t)c * NBLK + tid];
    r2[tid] = partials[(size_t)(64 + c) * NBLK + tid];
    __syncthreads();
#pragma unroll
    for (int s = 256; s > 0; s >>= 1) {
        if (tid < s) {
            r1[tid] += r1[tid + s];
            r2[tid] += r2[tid + s];
        }
        __syncthreads();
    }
    if (tid == 0) {
        const float invN = 1.0f / (float)NPIX;
        float mean = r1[0] * invN;
        float var  = r2[0] * invN - mean * mean;
        float sc   = gamma[c] * rsqrtf(var + BN_EPS);
        ss[c]      = sc;
        ss[64 + c] = beta[c] - mean * sc;
    }
}

// ---------------------------------------------------------------------------
// Kernel D: in-place normalize + clip (float4)
// ---------------------------------------------------------------------------
__global__ __launch_bounds__(256) void norm_kernel(float* __restrict__ out,
                                                   const float* __restrict__ ss) {
    int i = blockIdx.x * 256 + threadIdx.x;
    float4 v = ((float4*)out)[i];
    int oc = (i >> 8) & 63;
    float sc = ss[oc];
    float sh = ss[64 + oc];
    v.x = fminf(1.0f, fmaxf(-1.0f, fmaf(v.x, sc, sh)));
    v.y = fminf(1.0f, fmaxf(-1.0f, fmaf(v.y, sc, sh)));
    v.z = fminf(1.0f, fmaxf(-1.0f, fmaf(v.z, sc, sh)));
    v.w = fminf(1.0f, fmaxf(-1.0f, fmaf(v.w, sc, sh)));
    ((float4*)out)[i] = v;
}

// ---------------------------------------------------------------------------
extern "C" void kernel_launch(void* const* d_in, const int* in_sizes, int n_in,
                              void* d_out, int out_size, void* d_ws, size_t ws_size,
                              hipStream_t stream) {
    const float* x     = (const float*)d_in[0];
    const float* w     = (const float*)d_in[1];
    const float* gamma = (const float*)d_in[2];
    const float* beta  = (const float*)d_in[3];
    float* out = (float*)d_out;

    char*  wfrag    = (char*)d_ws;                          // 147456 B
    float* partials = (float*)((char*)d_ws + 147456);       // 128*512 floats
    float* ss       = partials + 128 * NBLK;                // 128 floats

    hipLaunchKernelGGL(prep_kernel, dim3(144), dim3(256), 0, stream, w, wfrag);
    hipLaunchKernelGGL(conv_kernel, dim3(4, 64), dim3(512), SMEM_TOTAL, stream,
                       x, wfrag, out, partials);
    hipLaunchKernelGGL(stats_kernel, dim3(64), dim3(512), 0, stream, partials, gamma, beta, ss);
    hipLaunchKernelGGL(norm_kernel, dim3(4096), dim3(256), 0, stream, out, ss);
}